// Round 3
// baseline (636.209 us; speedup 1.0000x reference)
//
#include <hip/hip_runtime.h>

typedef float f32x4 __attribute__((ext_vector_type(4)));
typedef __bf16 bf16x8 __attribute__((ext_vector_type(8)));

#define IMH 256
#define IMW 256
#define NCH 128
#define NHEAD 4
#define NWIN 1024
#define DWIN 2048
#define HW (IMH*IMW)

__device__ __forceinline__ unsigned short bf16u(float f) {
  __bf16 h = (__bf16)f;
  return __builtin_bit_cast(unsigned short, h);
}
__device__ __forceinline__ f32x4 fzero() { f32x4 z = {0.f, 0.f, 0.f, 0.f}; return z; }

// ---------------- prep: weights -> bf16 ----------------
__global__ void k_prep_w(const float* __restrict__ wq, const float* __restrict__ wk,
                         const float* __restrict__ wv, __bf16* __restrict__ wt) {
  int i = blockIdx.x * 256 + threadIdx.x;
  if (i < 16384) {
    wt[i]         = (__bf16)wq[i];
    wt[i + 16384] = (__bf16)wk[i];
    wt[i + 32768] = (__bf16)wv[i];
  }
}

// wo [o][c][3][3] -> wot [ky*3+kx][o][c]
__global__ void k_prep_wo(const float* __restrict__ wo, __bf16* __restrict__ wot) {
  int i = blockIdx.x * 256 + threadIdx.x;
  if (i < 9*16384) {
    int kk = i >> 14;
    int oc = i & 16383;
    wot[i] = (__bf16)wo[oc*9 + kk];
  }
}

// ---------------- qkv projection: one image row per block ----------------
// vt row order: d' = (py*8+px)*32 + dk  (pixel-offset-major, channel-minor)
__global__ __launch_bounds__(512)
void k_qkv(const float* __restrict__ x, const __bf16* __restrict__ wt,
           const float* __restrict__ bq, const float* __restrict__ bk,
           const float* __restrict__ bv,
           __bf16* __restrict__ qw, __bf16* __restrict__ kw, __bf16* __restrict__ vt) {
  __shared__ __align__(16) unsigned short xt[256*128];   // [w][c] swizzled, 64KB
  const int bidx = blockIdx.x;
  const int b = bidx >> 8, h = bidx & 255;
  const int py = h & 7, oy = h >> 3;
  const int t = threadIdx.x;
  // stage x^T (bf16) with XOR swizzle: byte = w*256 + ((c*2) ^ ((w&7)<<4))
  {
    const int w = t & 255, half = t >> 8;
    const float* xb = x + (size_t)(b*NCH)*HW + (size_t)h*IMW + w;
    #pragma unroll 8
    for (int i = 0; i < 32; ++i) {
      int c = half*64 + 2*i;
      float v0 = xb[(size_t)c*HW];
      float v1 = xb[(size_t)(c+1)*HW];
      unsigned int pk = (unsigned int)bf16u(v0) | ((unsigned int)bf16u(v1) << 16);
      *(unsigned int*)((char*)xt + (w*256 + ((c*2) ^ ((w&7)<<4)))) = pk;
    }
  }
  __syncthreads();
  const int lane = t & 63, wid = t >> 6;
  const int wm = wid >> 2, wn = wid & 3;          // o-tile 64*wm, w-tile 64*wn
  const int l15 = lane & 15, l4 = lane >> 4;
  for (int mat = 0; mat < 3; ++mat) {
    const __bf16* wmat = wt + mat*16384;
    const float* bias = (mat == 0) ? bq : ((mat == 1) ? bk : bv);
    f32x4 acc[4][4];
    #pragma unroll
    for (int i = 0; i < 4; ++i)
      #pragma unroll
      for (int j = 0; j < 4; ++j) acc[i][j] = fzero();
    #pragma unroll
    for (int kc = 0; kc < 4; ++kc) {
      bf16x8 a[4], bb[4];
      #pragma unroll
      for (int i = 0; i < 4; ++i) {
        int o = wm*64 + i*16 + l15;
        a[i] = *(const bf16x8*)(wmat + o*128 + kc*32 + l4*8);
      }
      #pragma unroll
      for (int j = 0; j < 4; ++j) {
        int wc = wn*64 + j*16 + l15;
        bb[j] = *(const bf16x8*)((const char*)xt + (wc*256 + ((kc*64 + l4*16) ^ ((wc&7)<<4))));
      }
      #pragma unroll
      for (int i = 0; i < 4; ++i)
        #pragma unroll
        for (int j = 0; j < 4; ++j)
          acc[i][j] = __builtin_amdgcn_mfma_f32_16x16x32_bf16(a[i], bb[j], acc[i][j], 0, 0, 0);
    }
    if (mat < 2) {
      __bf16* dst = (mat == 0) ? qw : kw;
      #pragma unroll
      for (int i = 0; i < 4; ++i)
        #pragma unroll
        for (int r = 0; r < 4; ++r) {
          int o = wm*64 + i*16 + l4*4 + r;
          float bi = bias[o];
          int nh = o >> 5, dk = o & 31;
          #pragma unroll
          for (int j = 0; j < 4; ++j) {
            int wcol = wn*64 + j*16 + l15;
            int ox = wcol >> 3, px = wcol & 7;
            size_t idx = (size_t)((b*NHEAD + nh)*NWIN + oy*32 + ox)*DWIN + dk*64 + py*8 + px;
            dst[idx] = (__bf16)(acc[i][j][r] + bi);
          }
        }
    } else {
      // V: repack through LDS so vt[d'][m] rows get 64B contiguous stores
      __syncthreads();
      unsigned short* rp = xt;   // reuse as [o][w] 128x256, XOR-swizzled per 512B o-slot
      #pragma unroll
      for (int i = 0; i < 4; ++i)
        #pragma unroll
        for (int r = 0; r < 4; ++r) {
          int o = wm*64 + i*16 + l4*4 + r;
          float bi = bias[o];
          #pragma unroll
          for (int j = 0; j < 4; ++j) {
            int wcol = wn*64 + j*16 + l15;
            *(unsigned short*)((char*)rp + o*512 + ((wcol*2) ^ ((o&7)<<4))) =
                bf16u(acc[i][j][r] + bi);
          }
        }
      __syncthreads();
      #pragma unroll
      for (int it = 0; it < 2; ++it) {
        int u = t + it*512;
        int o = u >> 3, px = u & 7;
        int nh = o >> 5, dk = o & 31;
        unsigned short tmp[32];
        #pragma unroll
        for (int ox = 0; ox < 32; ++ox)
          tmp[ox] = *(const unsigned short*)((const char*)rp + o*512 + (((ox*8+px)*2) ^ ((o&7)<<4)));
        __bf16* dstp = vt + ((size_t)(b*NHEAD + nh)*DWIN + (py*8+px)*32 + dk)*NWIN + oy*32;
        #pragma unroll
        for (int qq = 0; qq < 4; ++qq) {
          uint4 val;
          val.x = (unsigned int)tmp[qq*8+0] | ((unsigned int)tmp[qq*8+1] << 16);
          val.y = (unsigned int)tmp[qq*8+2] | ((unsigned int)tmp[qq*8+3] << 16);
          val.z = (unsigned int)tmp[qq*8+4] | ((unsigned int)tmp[qq*8+5] << 16);
          val.w = (unsigned int)tmp[qq*8+6] | ((unsigned int)tmp[qq*8+7] << 16);
          ((uint4*)dstp)[qq] = val;
        }
      }
    }
  }
}

// ---------------- shared 128x128 B^T GEMM tile (reg-staged, 2-barrier) ----------------
// LDS slot = 80B per 32-k row (64B data + 16B pad): frag ds_read_b128 lands on 8
// distinct bank-groups (R*20 mod 32) -> <=2-way conflicts (free), vs 8-way at 64B.
__device__ __forceinline__ void gemm_tile(const __bf16* __restrict__ A,
                                          const __bf16* __restrict__ B,
                                          const int lda, const int ldb, const int NT,
                                          unsigned short* Asm, unsigned short* Bsm,
                                          f32x4 (&acc)[4][4]) {
  const int t = threadIdx.x;
  const int lane = t & 63, wid = t >> 6;
  const int wm = wid >> 1, wn = wid & 1;
  const int l15 = lane & 15, l4 = lane >> 4;
  const int u0 = t, u1 = t + 256;
  const int ra0 = u0 >> 2, ca0 = u0 & 3;
  const int ra1 = u1 >> 2, ca1 = u1 & 3;
  uint4 ar0 = *(const uint4*)(A + ra0*lda + ca0*8);
  uint4 ar1 = *(const uint4*)(A + ra1*lda + ca1*8);
  uint4 br0 = *(const uint4*)(B + ra0*ldb + ca0*8);
  uint4 br1 = *(const uint4*)(B + ra1*ldb + ca1*8);
  for (int kt = 0; kt < NT; ++kt) {
    __syncthreads();
    *(uint4*)((char*)Asm + ra0*80 + ca0*16) = ar0;
    *(uint4*)((char*)Asm + ra1*80 + ca1*16) = ar1;
    *(uint4*)((char*)Bsm + ra0*80 + ca0*16) = br0;
    *(uint4*)((char*)Bsm + ra1*80 + ca1*16) = br1;
    __syncthreads();
    if (kt + 1 < NT) {       // issue next-tile loads; latency hides under MFMAs
      int k0 = (kt+1)*32;
      ar0 = *(const uint4*)(A + ra0*lda + k0 + ca0*8);
      ar1 = *(const uint4*)(A + ra1*lda + k0 + ca1*8);
      br0 = *(const uint4*)(B + ra0*ldb + k0 + ca0*8);
      br1 = *(const uint4*)(B + ra1*ldb + k0 + ca1*8);
    }
    bf16x8 a[4], bb[4];
    #pragma unroll
    for (int i = 0; i < 4; ++i)
      a[i] = *(const bf16x8*)((const char*)Asm + (wm*64 + i*16 + l15)*80 + l4*16);
    #pragma unroll
    for (int j = 0; j < 4; ++j)
      bb[j] = *(const bf16x8*)((const char*)Bsm + (wn*64 + j*16 + l15)*80 + l4*16);
    #pragma unroll
    for (int i = 0; i < 4; ++i)
      #pragma unroll
      for (int j = 0; j < 4; ++j)
        acc[i][j] = __builtin_amdgcn_mfma_f32_16x16x32_bf16(a[i], bb[j], acc[i][j], 0, 0, 0);
  }
}

// ---------------- scores = qw . kw^T / sqrt(d) ----------------
__global__ __launch_bounds__(256)
void k_scores(const __bf16* __restrict__ qw, const __bf16* __restrict__ kw,
              float* __restrict__ S) {
  __shared__ __align__(16) unsigned short Asm[5120], Bsm[5120];
  const int bnh = blockIdx.y;
  const int mt = blockIdx.x >> 3, nt = blockIdx.x & 7;
  const __bf16* A = qw + (size_t)bnh*NWIN*DWIN + (size_t)mt*128*DWIN;
  const __bf16* B = kw + (size_t)bnh*NWIN*DWIN + (size_t)nt*128*DWIN;
  f32x4 acc[4][4];
  #pragma unroll
  for (int i = 0; i < 4; ++i)
    #pragma unroll
    for (int j = 0; j < 4; ++j) acc[i][j] = fzero();
  gemm_tile(A, B, DWIN, DWIN, 64, Asm, Bsm, acc);
  const float scale = 0.022097086912079608f;  // 1/sqrt(2048)
  const int t = threadIdx.x, lane = t & 63, wid = t >> 6;
  const int wm = wid >> 1, wn = wid & 1, l15 = lane & 15, l4 = lane >> 4;
  float* Sb = S + (size_t)bnh*NWIN*NWIN + (size_t)(mt*128)*NWIN + nt*128;
  #pragma unroll
  for (int i = 0; i < 4; ++i)
    #pragma unroll
    for (int r = 0; r < 4; ++r) {
      int row = wm*64 + i*16 + l4*4 + r;
      #pragma unroll
      for (int j = 0; j < 4; ++j) {
        int col = wn*64 + j*16 + l15;
        Sb[(size_t)row*NWIN + col] = acc[i][j][r] * scale;
      }
    }
}

// ---------------- row softmax: S f32 -> P bf16 ----------------
__global__ __launch_bounds__(256)
void k_softmax(const float* __restrict__ S, __bf16* __restrict__ P) {
  __shared__ float red[8];
  const int row = blockIdx.x;
  const int t = threadIdx.x;
  const float4 v = ((const float4*)(S + (size_t)row*NWIN))[t];
  float m = fmaxf(fmaxf(v.x, v.y), fmaxf(v.z, v.w));
  for (int off = 1; off < 64; off <<= 1) m = fmaxf(m, __shfl_xor(m, off));
  const int wid = t >> 6, lane = t & 63;
  if (lane == 0) red[wid] = m;
  __syncthreads();
  m = fmaxf(fmaxf(red[0], red[1]), fmaxf(red[2], red[3]));
  float e0 = __expf(v.x - m), e1 = __expf(v.y - m), e2 = __expf(v.z - m), e3 = __expf(v.w - m);
  float s = e0 + e1 + e2 + e3;
  for (int off = 1; off < 64; off <<= 1) s += __shfl_xor(s, off);
  if (lane == 0) red[4 + wid] = s;
  __syncthreads();
  s = red[4] + red[5] + red[6] + red[7];
  float inv = 1.0f / s;
  ushort4 o;
  o.x = bf16u(e0*inv); o.y = bf16u(e1*inv); o.z = bf16u(e2*inv); o.w = bf16u(e3*inv);
  ((ushort4*)((unsigned short*)P + (size_t)row*NWIN))[t] = o;
}

// ---------------- y = P . V  (B = vt[d'][m]) -> y3[b][cgrp][h][w][c32] ----------------
__global__ __launch_bounds__(256)
void k_pv(const __bf16* __restrict__ P, const __bf16* __restrict__ vt,
          __bf16* __restrict__ y3) {
  __shared__ __align__(16) unsigned short Asm[5120], Bsm[5120];
  const int bnh = blockIdx.y;
  const int b = bnh >> 2, nh = bnh & 3;
  const int mt = blockIdx.x >> 4, nt = blockIdx.x & 15;
  const __bf16* A = P  + (size_t)bnh*NWIN*NWIN + (size_t)mt*128*NWIN;
  const __bf16* B = vt + (size_t)bnh*DWIN*NWIN + (size_t)nt*128*NWIN;
  f32x4 acc[4][4];
  #pragma unroll
  for (int i = 0; i < 4; ++i)
    #pragma unroll
    for (int j = 0; j < 4; ++j) acc[i][j] = fzero();
  gemm_tile(A, B, NWIN, NWIN, 32, Asm, Bsm, acc);
  const int t = threadIdx.x, lane = t & 63, wid = t >> 6;
  const int wm = wid >> 1, wn = wid & 1, l15 = lane & 15, l4 = lane >> 4;
  unsigned short* yu = (unsigned short*)y3;
  const size_t cbase = (size_t)(b*NHEAD + nh)*65536*32;
  #pragma unroll
  for (int i = 0; i < 4; ++i)
    #pragma unroll
    for (int r = 0; r < 4; ++r) {
      int n = mt*128 + wm*64 + i*16 + l4*4 + r;
      int oyy = n >> 5, oxx = n & 31;
      #pragma unroll
      for (int j = 0; j < 4; ++j) {
        // d' = nt*128 + wn*64 + j*16 + l15 ; pp = d'>>5 ; dk = d'&31 (l15<16)
        int pp = nt*4 + wn*2 + (j >> 1);
        int dk = (j & 1)*16 + l15;
        int hh = oyy*8 + (pp >> 3), ww = oxx*8 + (pp & 7);
        yu[cbase + ((size_t)hh*256 + ww)*32 + dk] = bf16u(acc[i][j][r]);
      }
    }
}

// ---------------- 3x3 reflect conv + bias + LeakyReLU ----------------
// y3 layout [b][cgrp4][h][w][c32]: staging = uint4 global loads + b128 LDS writes,
// no division. LDS slot 80B -> frag reads <=2-way bank conflicts.
__global__ __launch_bounds__(256)
void k_conv(const __bf16* __restrict__ y3, const __bf16* __restrict__ wot,
            const float* __restrict__ bo, float* __restrict__ out) {
  __shared__ __align__(16) unsigned short ylds[15840];  // 396 slots * 80B
  const int bid = blockIdx.x;
  const int half = bid & 1, h = (bid >> 1) & 255, b = bid >> 9;
  const int w0 = half * 128;
  const int t = threadIdx.x;
  const int hm1 = (h == 0) ? 1 : h - 1;
  const int hp1 = (h == 255) ? 254 : h + 1;
  const int lane = t & 63, wid = t >> 6;
  const int wm = wid >> 1, wn = wid & 1, l15 = lane & 15, l4 = lane >> 4;
  f32x4 acc[4][4];
  #pragma unroll
  for (int i = 0; i < 4; ++i)
    #pragma unroll
    for (int j = 0; j < 4; ++j) acc[i][j] = fzero();
  const unsigned short* yu = (const unsigned short*)y3;
  for (int cc = 0; cc < 4; ++cc) {
    const size_t cbase = (size_t)(b*NHEAD + cc)*65536*32;
    __syncthreads();
    // main: 3 rows x 128 wl x 4 segs = 1536 uint4 in 6 full iterations
    #pragma unroll
    for (int it = 0; it < 6; ++it) {
      int u = it*256 + t;
      int seg = u & 3, wl = (u >> 2) & 127, rowr = u >> 9;
      int hh = (rowr == 0) ? hm1 : ((rowr == 1) ? h : hp1);
      int gw = w0 - 1 + wl;
      gw = (gw < 0) ? 1 : ((gw > 255) ? 254 : gw);
      uint4 val = *(const uint4*)(yu + cbase + ((size_t)hh*256 + gw)*32 + seg*8);
      *(uint4*)((char*)ylds + (rowr*132 + wl)*80 + seg*16) = val;
    }
    // tail: wl in {128,129}: 3 rows x 2 wl x 4 segs = 24 uint4
    if (t < 24) {
      int seg = t & 3, wl = 128 + ((t >> 2) & 1), rowr = t >> 3;
      int hh = (rowr == 0) ? hm1 : ((rowr == 1) ? h : hp1);
      int gw = w0 - 1 + wl;
      gw = (gw < 0) ? 1 : ((gw > 255) ? 254 : gw);
      uint4 val = *(const uint4*)(yu + cbase + ((size_t)hh*256 + gw)*32 + seg*8);
      *(uint4*)((char*)ylds + (rowr*132 + wl)*80 + seg*16) = val;
    }
    __syncthreads();
    #pragma unroll
    for (int kk = 0; kk < 9; ++kk) {
      const int ky = kk / 3, kx = kk % 3;
      bf16x8 a[4], bb[4];
      #pragma unroll
      for (int i = 0; i < 4; ++i) {
        int o = wm*64 + i*16 + l15;
        a[i] = *(const bf16x8*)(wot + ((size_t)kk*128 + o)*128 + cc*32 + l4*8);
      }
      #pragma unroll
      for (int j = 0; j < 4; ++j) {
        int px = wn*64 + j*16 + l15;
        int R = ky*132 + px + kx;
        bb[j] = *(const bf16x8*)((const char*)ylds + R*80 + l4*16);
      }
      #pragma unroll
      for (int i = 0; i < 4; ++i)
        #pragma unroll
        for (int j = 0; j < 4; ++j)
          acc[i][j] = __builtin_amdgcn_mfma_f32_16x16x32_bf16(a[i], bb[j], acc[i][j], 0, 0, 0);
    }
  }
  #pragma unroll
  for (int i = 0; i < 4; ++i)
    #pragma unroll
    for (int r = 0; r < 4; ++r) {
      int o = wm*64 + i*16 + l4*4 + r;
      float bi = bo[o];
      #pragma unroll
      for (int j = 0; j < 4; ++j) {
        int px = wn*64 + j*16 + l15;
        float v = acc[i][j][r] + bi;
        v = (v > 0.f) ? v : 0.2f * v;
        out[(size_t)((b*NCH + o)*IMH + h)*IMW + w0 + px] = v;
      }
    }
}

// ---------------- launcher ----------------
extern "C" void kernel_launch(void* const* d_in, const int* in_sizes, int n_in,
                              void* d_out, int out_size, void* d_ws, size_t ws_size,
                              hipStream_t stream) {
  (void)in_sizes; (void)n_in; (void)out_size; (void)ws_size;
  const float* x  = (const float*)d_in[0];
  // d_in[1] = m : mask is a no-op in the reference
  const float* wq = (const float*)d_in[2];
  const float* bq = (const float*)d_in[3];
  const float* wk = (const float*)d_in[4];
  const float* bk = (const float*)d_in[5];
  const float* wv = (const float*)d_in[6];
  const float* bv = (const float*)d_in[7];
  const float* wo = (const float*)d_in[8];
  const float* bo = (const float*)d_in[9];
  float* out = (float*)d_out;
  char* ws = (char*)d_ws;
  // region A [0,64MB): qw, later P (first 32MB)
  // region B [64,128MB): kw, later wot (written after scores)
  // region C [128,192MB): vt
  // region D [192,256MB): wt (transient), then S f32, then y3 bf16
  __bf16* qw  = (__bf16*)(ws + 0);
  __bf16* kw  = (__bf16*)(ws + 67108864);
  __bf16* vt  = (__bf16*)(ws + 134217728);
  float*  S   = (float*)(ws + 201326592);
  __bf16* P   = (__bf16*)(ws + 0);
  __bf16* y3  = (__bf16*)(ws + 201326592);
  __bf16* wt  = (__bf16*)(ws + 201326592);
  __bf16* wot = (__bf16*)(ws + 67108864);

  k_prep_w<<<64, 256, 0, stream>>>(wq, wk, wv, wt);
  k_qkv<<<1024, 512, 0, stream>>>(x, wt, bq, bk, bv, qw, kw, vt);
  k_scores<<<dim3(64, 16), 256, 0, stream>>>(qw, kw, S);
  k_prep_wo<<<576, 256, 0, stream>>>(wo, wot);
  k_softmax<<<16384, 256, 0, stream>>>(S, P);
  k_pv<<<dim3(128, 16), 256, 0, stream>>>(P, vt, y3);
  k_conv<<<2048, 256, 0, stream>>>(y3, wot, bo, out);
}

// Round 4
// 588.338 us; speedup vs baseline: 1.0814x; 1.0814x over previous
//
#include <hip/hip_runtime.h>

typedef float f32x4 __attribute__((ext_vector_type(4)));
typedef __bf16 bf16x8 __attribute__((ext_vector_type(8)));

#define IMH 256
#define IMW 256
#define NCH 128
#define NHEAD 4
#define NWIN 1024
#define DWIN 2048
#define HW (IMH*IMW)

__device__ __forceinline__ unsigned short bf16u(float f) {
  __bf16 h = (__bf16)f;
  return __builtin_bit_cast(unsigned short, h);
}
__device__ __forceinline__ f32x4 fzero() { f32x4 z = {0.f, 0.f, 0.f, 0.f}; return z; }

// ---------------- prep: weights -> bf16 ----------------
__global__ void k_prep_w(const float* __restrict__ wq, const float* __restrict__ wk,
                         const float* __restrict__ wv, __bf16* __restrict__ wt) {
  int i = blockIdx.x * 256 + threadIdx.x;
  if (i < 16384) {
    wt[i]         = (__bf16)wq[i];
    wt[i + 16384] = (__bf16)wk[i];
    wt[i + 32768] = (__bf16)wv[i];
  }
}

// wo [o][c][3][3] -> wot [ky*3+kx][o][c]
__global__ void k_prep_wo(const float* __restrict__ wo, __bf16* __restrict__ wot) {
  int i = blockIdx.x * 256 + threadIdx.x;
  if (i < 9*16384) {
    int kk = i >> 14;
    int oc = i & 16383;
    wot[i] = (__bf16)wo[oc*9 + kk];
  }
}

// ---------------- qkv projection: one half image row per block ----------------
// q/k d-order: d' = py*256 + px*32 + dk  (consistent q&k permutation -> scores invariant)
// vt row order: d'' = py*256 + px*32 + dk (d''>>5 = py*8+px, same decode as before)
// All epilogues repack acc through LDS (rp) -> contiguous 64B vector stores.
__global__ __launch_bounds__(512)
void k_qkv(const float* __restrict__ x, const __bf16* __restrict__ wt,
           const float* __restrict__ bq, const float* __restrict__ bk,
           const float* __restrict__ bv,
           __bf16* __restrict__ qw, __bf16* __restrict__ kw, __bf16* __restrict__ vt) {
  __shared__ __align__(16) unsigned short xt[16384];   // [w=128][c=128] swizzled 256B slots
  __shared__ __align__(16) unsigned short rp[16384];   // [o=128][w=128] swizzled 256B slots
  const int bidx = blockIdx.x;
  const int half = bidx & 1, h = (bidx >> 1) & 255, b = bidx >> 9;
  const int py = h & 7, oy = h >> 3;
  const int w0 = half * 128;
  const int t = threadIdx.x;
  // stage x^T (bf16): xt byte = w*256 + ((c*2) ^ ((w&7)<<4)); b128 writes
  {
    const int w = t & 127, cg0 = (t >> 7) * 8;   // cg0 in {0,8,16,24}
    const float* xb = x + (size_t)(b*NCH)*HW + (size_t)h*IMW + w0 + w;
    #pragma unroll
    for (int c0i = 0; c0i < 4; ++c0i) {
      int c0 = cg0 + c0i*32;
      unsigned int pk[4];
      #pragma unroll
      for (int q = 0; q < 4; ++q) {
        float v0 = xb[(size_t)(c0 + 2*q)*HW];
        float v1 = xb[(size_t)(c0 + 2*q + 1)*HW];
        pk[q] = (unsigned int)bf16u(v0) | ((unsigned int)bf16u(v1) << 16);
      }
      uint4 val; val.x = pk[0]; val.y = pk[1]; val.z = pk[2]; val.w = pk[3];
      *(uint4*)((char*)xt + w*256 + ((c0*2) ^ ((w&7)<<4))) = val;
    }
  }
  __syncthreads();
  const int lane = t & 63, wid = t >> 6;
  const int wm = wid >> 2, wn = wid & 3;          // o-tile 64*wm, w-tile 32*wn
  const int l15 = lane & 15, l4 = lane >> 4;
  for (int mat = 0; mat < 3; ++mat) {
    const __bf16* wmat = wt + mat*16384;
    const float* bias = (mat == 0) ? bq : ((mat == 1) ? bk : bv);
    f32x4 acc[4][2];
    #pragma unroll
    for (int i = 0; i < 4; ++i)
      #pragma unroll
      for (int j = 0; j < 2; ++j) acc[i][j] = fzero();
    #pragma unroll
    for (int kc = 0; kc < 4; ++kc) {
      bf16x8 a[4], bb[2];
      #pragma unroll
      for (int i = 0; i < 4; ++i) {
        int o = wm*64 + i*16 + l15;
        a[i] = *(const bf16x8*)(wmat + o*128 + kc*32 + l4*8);
      }
      #pragma unroll
      for (int j = 0; j < 2; ++j) {
        int wc = wn*32 + j*16 + l15;
        bb[j] = *(const bf16x8*)((const char*)xt + (wc*256 + ((kc*64 + l4*16) ^ ((wc&7)<<4))));
      }
      #pragma unroll
      for (int i = 0; i < 4; ++i)
        #pragma unroll
        for (int j = 0; j < 2; ++j)
          acc[i][j] = __builtin_amdgcn_mfma_f32_16x16x32_bf16(a[i], bb[j], acc[i][j], 0, 0, 0);
    }
    // repack acc+bias -> rp[o][w] (swizzled)
    #pragma unroll
    for (int i = 0; i < 4; ++i)
      #pragma unroll
      for (int r = 0; r < 4; ++r) {
        int o = wm*64 + i*16 + l4*4 + r;
        float bi = bias[o];
        #pragma unroll
        for (int j = 0; j < 2; ++j) {
          int w = wn*32 + j*16 + l15;
          *(unsigned short*)((char*)rp + o*256 + ((w*2) ^ ((o&7)<<4))) =
              bf16u(acc[i][j][r] + bi);
        }
      }
    __syncthreads();
    if (mat < 2) {
      __bf16* dst = (mat == 0) ? qw : kw;
      const int px = t & 7, oxl = (t >> 3) & 15, nh = t >> 7;
      const int n = oy*32 + half*16 + oxl;
      unsigned short v[32];
      #pragma unroll
      for (int dk = 0; dk < 32; ++dk) {
        int o = nh*32 + dk;
        v[dk] = *(const unsigned short*)((const char*)rp + o*256 +
                  (((oxl*8 + px)*2) ^ ((o&7)<<4)));
      }
      unsigned short* dp = (unsigned short*)dst +
          ((size_t)(b*NHEAD + nh)*NWIN + n)*DWIN + py*256 + px*32;
      #pragma unroll
      for (int qq = 0; qq < 4; ++qq) {
        uint4 val;
        val.x = (unsigned int)v[qq*8+0] | ((unsigned int)v[qq*8+1] << 16);
        val.y = (unsigned int)v[qq*8+2] | ((unsigned int)v[qq*8+3] << 16);
        val.z = (unsigned int)v[qq*8+4] | ((unsigned int)v[qq*8+5] << 16);
        val.w = (unsigned int)v[qq*8+6] | ((unsigned int)v[qq*8+7] << 16);
        ((uint4*)dp)[qq] = val;
      }
    } else {
      #pragma unroll
      for (int it = 0; it < 2; ++it) {
        int u = it*512 + t;
        int px = u & 7, dk = (u >> 3) & 31, nh = u >> 8;
        int o = nh*32 + dk;
        unsigned short v[16];
        #pragma unroll
        for (int ox = 0; ox < 16; ++ox)
          v[ox] = *(const unsigned short*)((const char*)rp + o*256 +
                    (((ox*8 + px)*2) ^ ((o&7)<<4)));
        unsigned short* dp = (unsigned short*)vt +
            ((size_t)(b*NHEAD + nh)*DWIN + py*256 + px*32 + dk)*NWIN + oy*32 + half*16;
        #pragma unroll
        for (int qq = 0; qq < 2; ++qq) {
          uint4 val;
          val.x = (unsigned int)v[qq*8+0] | ((unsigned int)v[qq*8+1] << 16);
          val.y = (unsigned int)v[qq*8+2] | ((unsigned int)v[qq*8+3] << 16);
          val.z = (unsigned int)v[qq*8+4] | ((unsigned int)v[qq*8+5] << 16);
          val.w = (unsigned int)v[qq*8+6] | ((unsigned int)v[qq*8+7] << 16);
          ((uint4*)dp)[qq] = val;
        }
      }
    }
    __syncthreads();
  }
}

// ---------------- shared 128x128 B^T GEMM tile (reg-staged, 2-barrier) ----------------
// LDS slot = 80B per 32-k row (64B data + 16B pad): frag ds_read_b128 lands on 8
// distinct bank-groups (R*20 mod 32) -> <=2-way conflicts (free), vs 8-way at 64B.
__device__ __forceinline__ void gemm_tile(const __bf16* __restrict__ A,
                                          const __bf16* __restrict__ B,
                                          const int lda, const int ldb, const int NT,
                                          unsigned short* Asm, unsigned short* Bsm,
                                          f32x4 (&acc)[4][4]) {
  const int t = threadIdx.x;
  const int lane = t & 63, wid = t >> 6;
  const int wm = wid >> 1, wn = wid & 1;
  const int l15 = lane & 15, l4 = lane >> 4;
  const int u0 = t, u1 = t + 256;
  const int ra0 = u0 >> 2, ca0 = u0 & 3;
  const int ra1 = u1 >> 2, ca1 = u1 & 3;
  uint4 ar0 = *(const uint4*)(A + ra0*lda + ca0*8);
  uint4 ar1 = *(const uint4*)(A + ra1*lda + ca1*8);
  uint4 br0 = *(const uint4*)(B + ra0*ldb + ca0*8);
  uint4 br1 = *(const uint4*)(B + ra1*ldb + ca1*8);
  for (int kt = 0; kt < NT; ++kt) {
    __syncthreads();
    *(uint4*)((char*)Asm + ra0*80 + ca0*16) = ar0;
    *(uint4*)((char*)Asm + ra1*80 + ca1*16) = ar1;
    *(uint4*)((char*)Bsm + ra0*80 + ca0*16) = br0;
    *(uint4*)((char*)Bsm + ra1*80 + ca1*16) = br1;
    __syncthreads();
    if (kt + 1 < NT) {       // issue next-tile loads; latency hides under MFMAs
      int k0 = (kt+1)*32;
      ar0 = *(const uint4*)(A + ra0*lda + k0 + ca0*8);
      ar1 = *(const uint4*)(A + ra1*lda + k0 + ca1*8);
      br0 = *(const uint4*)(B + ra0*ldb + k0 + ca0*8);
      br1 = *(const uint4*)(B + ra1*ldb + k0 + ca1*8);
    }
    bf16x8 a[4], bb[4];
    #pragma unroll
    for (int i = 0; i < 4; ++i)
      a[i] = *(const bf16x8*)((const char*)Asm + (wm*64 + i*16 + l15)*80 + l4*16);
    #pragma unroll
    for (int j = 0; j < 4; ++j)
      bb[j] = *(const bf16x8*)((const char*)Bsm + (wn*64 + j*16 + l15)*80 + l4*16);
    #pragma unroll
    for (int i = 0; i < 4; ++i)
      #pragma unroll
      for (int j = 0; j < 4; ++j)
        acc[i][j] = __builtin_amdgcn_mfma_f32_16x16x32_bf16(a[i], bb[j], acc[i][j], 0, 0, 0);
  }
}

// ---------------- scores = qw . kw^T / sqrt(d) ----------------
__global__ __launch_bounds__(256)
void k_scores(const __bf16* __restrict__ qw, const __bf16* __restrict__ kw,
              float* __restrict__ S) {
  __shared__ __align__(16) unsigned short Asm[5120], Bsm[5120];
  const int bnh = blockIdx.y;
  const int mt = blockIdx.x >> 3, nt = blockIdx.x & 7;
  const __bf16* A = qw + (size_t)bnh*NWIN*DWIN + (size_t)mt*128*DWIN;
  const __bf16* B = kw + (size_t)bnh*NWIN*DWIN + (size_t)nt*128*DWIN;
  f32x4 acc[4][4];
  #pragma unroll
  for (int i = 0; i < 4; ++i)
    #pragma unroll
    for (int j = 0; j < 4; ++j) acc[i][j] = fzero();
  gemm_tile(A, B, DWIN, DWIN, 64, Asm, Bsm, acc);
  const float scale = 0.022097086912079608f;  // 1/sqrt(2048)
  const int t = threadIdx.x, lane = t & 63, wid = t >> 6;
  const int wm = wid >> 1, wn = wid & 1, l15 = lane & 15, l4 = lane >> 4;
  float* Sb = S + (size_t)bnh*NWIN*NWIN + (size_t)(mt*128)*NWIN + nt*128;
  #pragma unroll
  for (int i = 0; i < 4; ++i)
    #pragma unroll
    for (int r = 0; r < 4; ++r) {
      int row = wm*64 + i*16 + l4*4 + r;
      #pragma unroll
      for (int j = 0; j < 4; ++j) {
        int col = wn*64 + j*16 + l15;
        Sb[(size_t)row*NWIN + col] = acc[i][j][r] * scale;
      }
    }
}

// ---------------- row softmax: S f32 -> P bf16 ----------------
__global__ __launch_bounds__(256)
void k_softmax(const float* __restrict__ S, __bf16* __restrict__ P) {
  __shared__ float red[8];
  const int row = blockIdx.x;
  const int t = threadIdx.x;
  const float4 v = ((const float4*)(S + (size_t)row*NWIN))[t];
  float m = fmaxf(fmaxf(v.x, v.y), fmaxf(v.z, v.w));
  for (int off = 1; off < 64; off <<= 1) m = fmaxf(m, __shfl_xor(m, off));
  const int wid = t >> 6, lane = t & 63;
  if (lane == 0) red[wid] = m;
  __syncthreads();
  m = fmaxf(fmaxf(red[0], red[1]), fmaxf(red[2], red[3]));
  float e0 = __expf(v.x - m), e1 = __expf(v.y - m), e2 = __expf(v.z - m), e3 = __expf(v.w - m);
  float s = e0 + e1 + e2 + e3;
  for (int off = 1; off < 64; off <<= 1) s += __shfl_xor(s, off);
  if (lane == 0) red[4 + wid] = s;
  __syncthreads();
  s = red[4] + red[5] + red[6] + red[7];
  float inv = 1.0f / s;
  ushort4 o;
  o.x = bf16u(e0*inv); o.y = bf16u(e1*inv); o.z = bf16u(e2*inv); o.w = bf16u(e3*inv);
  ((ushort4*)((unsigned short*)P + (size_t)row*NWIN))[t] = o;
}

// ---------------- y = P . V  (B = vt[d''][m]) -> y3[b][cgrp][h][w][c32] ----------------
__global__ __launch_bounds__(256)
void k_pv(const __bf16* __restrict__ P, const __bf16* __restrict__ vt,
          __bf16* __restrict__ y3) {
  __shared__ __align__(16) unsigned short Asm[5120], Bsm[5120];
  const int bnh = blockIdx.y;
  const int b = bnh >> 2, nh = bnh & 3;
  const int mt = blockIdx.x >> 4, nt = blockIdx.x & 15;
  const __bf16* A = P  + (size_t)bnh*NWIN*NWIN + (size_t)mt*128*NWIN;
  const __bf16* B = vt + (size_t)bnh*DWIN*NWIN + (size_t)nt*128*NWIN;
  f32x4 acc[4][4];
  #pragma unroll
  for (int i = 0; i < 4; ++i)
    #pragma unroll
    for (int j = 0; j < 4; ++j) acc[i][j] = fzero();
  gemm_tile(A, B, NWIN, NWIN, 32, Asm, Bsm, acc);
  const int t = threadIdx.x, lane = t & 63, wid = t >> 6;
  const int wm = wid >> 1, wn = wid & 1, l15 = lane & 15, l4 = lane >> 4;
  unsigned short* yu = (unsigned short*)y3;
  const size_t cbase = (size_t)(b*NHEAD + nh)*65536*32;
  #pragma unroll
  for (int i = 0; i < 4; ++i)
    #pragma unroll
    for (int r = 0; r < 4; ++r) {
      int n = mt*128 + wm*64 + i*16 + l4*4 + r;
      int oyy = n >> 5, oxx = n & 31;
      #pragma unroll
      for (int j = 0; j < 4; ++j) {
        // d'' = nt*128 + wn*64 + j*16 + l15 ; pp = d''>>5 ; dk = d''&31 (l15<16)
        int pp = nt*4 + wn*2 + (j >> 1);
        int dk = (j & 1)*16 + l15;
        int hh = oyy*8 + (pp >> 3), ww = oxx*8 + (pp & 7);
        yu[cbase + ((size_t)hh*256 + ww)*32 + dk] = bf16u(acc[i][j][r]);
      }
    }
}

// ---------------- 3x3 reflect conv + bias + LeakyReLU ----------------
// y3 layout [b][cgrp4][h][w][c32]: staging = uint4 global loads + b128 LDS writes,
// no division. LDS slot 80B -> frag reads <=2-way bank conflicts.
__global__ __launch_bounds__(256)
void k_conv(const __bf16* __restrict__ y3, const __bf16* __restrict__ wot,
            const float* __restrict__ bo, float* __restrict__ out) {
  __shared__ __align__(16) unsigned short ylds[15840];  // 396 slots * 80B
  const int bid = blockIdx.x;
  const int half = bid & 1, h = (bid >> 1) & 255, b = bid >> 9;
  const int w0 = half * 128;
  const int t = threadIdx.x;
  const int hm1 = (h == 0) ? 1 : h - 1;
  const int hp1 = (h == 255) ? 254 : h + 1;
  const int lane = t & 63, wid = t >> 6;
  const int wm = wid >> 1, wn = wid & 1, l15 = lane & 15, l4 = lane >> 4;
  f32x4 acc[4][4];
  #pragma unroll
  for (int i = 0; i < 4; ++i)
    #pragma unroll
    for (int j = 0; j < 4; ++j) acc[i][j] = fzero();
  const unsigned short* yu = (const unsigned short*)y3;
  for (int cc = 0; cc < 4; ++cc) {
    const size_t cbase = (size_t)(b*NHEAD + cc)*65536*32;
    __syncthreads();
    // main: 3 rows x 128 wl x 4 segs = 1536 uint4 in 6 full iterations
    #pragma unroll
    for (int it = 0; it < 6; ++it) {
      int u = it*256 + t;
      int seg = u & 3, wl = (u >> 2) & 127, rowr = u >> 9;
      int hh = (rowr == 0) ? hm1 : ((rowr == 1) ? h : hp1);
      int gw = w0 - 1 + wl;
      gw = (gw < 0) ? 1 : ((gw > 255) ? 254 : gw);
      uint4 val = *(const uint4*)(yu + cbase + ((size_t)hh*256 + gw)*32 + seg*8);
      *(uint4*)((char*)ylds + (rowr*132 + wl)*80 + seg*16) = val;
    }
    // tail: wl in {128,129}: 3 rows x 2 wl x 4 segs = 24 uint4
    if (t < 24) {
      int seg = t & 3, wl = 128 + ((t >> 2) & 1), rowr = t >> 3;
      int hh = (rowr == 0) ? hm1 : ((rowr == 1) ? h : hp1);
      int gw = w0 - 1 + wl;
      gw = (gw < 0) ? 1 : ((gw > 255) ? 254 : gw);
      uint4 val = *(const uint4*)(yu + cbase + ((size_t)hh*256 + gw)*32 + seg*8);
      *(uint4*)((char*)ylds + (rowr*132 + wl)*80 + seg*16) = val;
    }
    __syncthreads();
    #pragma unroll
    for (int kk = 0; kk < 9; ++kk) {
      const int ky = kk / 3, kx = kk % 3;
      bf16x8 a[4], bb[4];
      #pragma unroll
      for (int i = 0; i < 4; ++i) {
        int o = wm*64 + i*16 + l15;
        a[i] = *(const bf16x8*)(wot + ((size_t)kk*128 + o)*128 + cc*32 + l4*8);
      }
      #pragma unroll
      for (int j = 0; j < 4; ++j) {
        int px = wn*64 + j*16 + l15;
        int R = ky*132 + px + kx;
        bb[j] = *(const bf16x8*)((const char*)ylds + R*80 + l4*16);
      }
      #pragma unroll
      for (int i = 0; i < 4; ++i)
        #pragma unroll
        for (int j = 0; j < 4; ++j)
          acc[i][j] = __builtin_amdgcn_mfma_f32_16x16x32_bf16(a[i], bb[j], acc[i][j], 0, 0, 0);
    }
  }
  #pragma unroll
  for (int i = 0; i < 4; ++i)
    #pragma unroll
    for (int r = 0; r < 4; ++r) {
      int o = wm*64 + i*16 + l4*4 + r;
      float bi = bo[o];
      #pragma unroll
      for (int j = 0; j < 4; ++j) {
        int px = wn*64 + j*16 + l15;
        float v = acc[i][j][r] + bi;
        v = (v > 0.f) ? v : 0.2f * v;
        out[(size_t)((b*NCH + o)*IMH + h)*IMW + w0 + px] = v;
      }
    }
}

// ---------------- launcher ----------------
extern "C" void kernel_launch(void* const* d_in, const int* in_sizes, int n_in,
                              void* d_out, int out_size, void* d_ws, size_t ws_size,
                              hipStream_t stream) {
  (void)in_sizes; (void)n_in; (void)out_size; (void)ws_size;
  const float* x  = (const float*)d_in[0];
  // d_in[1] = m : mask is a no-op in the reference
  const float* wq = (const float*)d_in[2];
  const float* bq = (const float*)d_in[3];
  const float* wk = (const float*)d_in[4];
  const float* bk = (const float*)d_in[5];
  const float* wv = (const float*)d_in[6];
  const float* bv = (const float*)d_in[7];
  const float* wo = (const float*)d_in[8];
  const float* bo = (const float*)d_in[9];
  float* out = (float*)d_out;
  char* ws = (char*)d_ws;
  // region A [0,64MB): qw, later P (first 32MB)
  // region B [64,128MB): kw, later wot (written after scores)
  // region C [128,192MB): vt
  // region D [192,256MB): wt (transient), then S f32, then y3 bf16
  __bf16* qw  = (__bf16*)(ws + 0);
  __bf16* kw  = (__bf16*)(ws + 67108864);
  __bf16* vt  = (__bf16*)(ws + 134217728);
  float*  S   = (float*)(ws + 201326592);
  __bf16* P   = (__bf16*)(ws + 0);
  __bf16* y3  = (__bf16*)(ws + 201326592);
  __bf16* wt  = (__bf16*)(ws + 201326592);
  __bf16* wot = (__bf16*)(ws + 67108864);

  k_prep_w<<<64, 256, 0, stream>>>(wq, wk, wv, wt);
  k_qkv<<<2048, 512, 0, stream>>>(x, wt, bq, bk, bv, qw, kw, vt);
  k_scores<<<dim3(64, 16), 256, 0, stream>>>(qw, kw, S);
  k_prep_wo<<<576, 256, 0, stream>>>(wo, wot);
  k_softmax<<<16384, 256, 0, stream>>>(S, P);
  k_pv<<<dim3(128, 16), 256, 0, stream>>>(P, vt, y3);
  k_conv<<<2048, 256, 0, stream>>>(y3, wot, bo, out);
}